// Round 9
// baseline (146.849 us; speedup 1.0000x reference)
//
#include <hip/hip_runtime.h>

// B=8, F=4, T=S=1024, C=32, C2=64, NH=2, HD=16
// Inputs fp32, output fp32. q/k/v staged as bf16 for MFMA attention.
#define T_LEN 1024

typedef __attribute__((ext_vector_type(8))) short short8;   // 8 bf16 = 4 VGPR (MFMA A/B frag)
typedef __attribute__((ext_vector_type(4))) short short4v;
typedef __attribute__((ext_vector_type(4))) float float4v;  // MFMA C/D frag

__device__ __forceinline__ float gelu_exact(float x) {
    return 0.5f * x * (1.0f + erff(x * 0.70710678118654752440f));
}
__device__ __forceinline__ unsigned short f2bf(float f) {   // round-to-nearest-even
    unsigned u = __float_as_uint(f);
    u += 0x7fffu + ((u >> 16) & 1u);
    return (unsigned short)(u >> 16);
}

// ---------------------------------------------------------------------------
// MFMA TCL for q/k/v: one dispatch, 768 blocks, 64 t-rows/block.
// conv as im2col GEMM (48 MFMAs) + proj GEMM (16 MFMAs). See R7 notes.
// ---------------------------------------------------------------------------
__global__ __launch_bounds__(256) void tcl_mfma(
    const float* __restrict__ cd, const float* __restrict__ pkv,
    const float* __restrict__ wqc, const float* __restrict__ bqc,
    const float* __restrict__ wqp, const float* __restrict__ bqp,
    const float* __restrict__ wkc, const float* __restrict__ bkc,
    const float* __restrict__ wkp, const float* __restrict__ bkp,
    const float* __restrict__ wvc, const float* __restrict__ bvc,
    const float* __restrict__ wvp, const float* __restrict__ bvp,
    unsigned short* __restrict__ qbf, unsigned short* __restrict__ kbf,
    unsigned short* __restrict__ vtbf)
{
    __shared__ __align__(16) unsigned short Abuf[64 * 96];
    __shared__ __align__(16) unsigned short WbT[64 * 96];
    __shared__ __align__(16) unsigned short Hb[64 * 72];
    __shared__ __align__(16) unsigned short WpB[32 * 72];

    const int tid = threadIdx.x;
    const int gb = blockIdx.x;

    const float *src, *wc, *bc, *wp, *bp;
    unsigned short* outb;
    int n, mode;
    if (gb < 512)      { n = gb >> 4;          src = cd;  wc = wqc; bc = bqc; wp = wqp; bp = bqp; outb = qbf;  mode = 0; }
    else if (gb < 640) { n = (gb - 512) >> 4;  src = pkv; wc = wkc; bc = bkc; wp = wkp; bp = bkp; outb = kbf;  mode = 0; }
    else               { n = (gb - 640) >> 4;  src = pkv; wc = wvc; bc = bvc; wp = wvp; bp = bvp; outb = vtbf; mode = 1; }
    const int t0 = (gb & 15) * 64;

#pragma unroll
    for (int it = 0; it < 6; ++it) {
        int s = (tid + it * 256) >> 3;
        int sub = tid & 7;
        int t = s / 3, tap = s - t * 3;
        int tau = t0 + t - 2 + tap;
        float4 xv = make_float4(0.f, 0.f, 0.f, 0.f);
        if (tau >= 0) xv = *(const float4*)&src[((size_t)n * T_LEN + tau) * 32 + sub * 4];
        short4v pk = { (short)f2bf(xv.x), (short)f2bf(xv.y),
                       (short)f2bf(xv.z), (short)f2bf(xv.w) };
        *(short4v*)&Abuf[t * 96 + tap * 32 + sub * 4] = pk;
    }
#pragma unroll
    for (int it = 0; it < 6; ++it) {
        int i4 = tid + it * 256;
        int idx = i4 * 4;
        int o = idx / 96, r = idx - o * 96;
        float4 w4 = *(const float4*)&wc[idx];
        float we[4] = { w4.x, w4.y, w4.z, w4.w };
#pragma unroll
        for (int e = 0; e < 4; ++e) {
            int re = r + e, c = re / 3, tap = re - c * 3;
            WbT[o * 96 + tap * 32 + c] = f2bf(we[e]);
        }
    }
#pragma unroll
    for (int it = 0; it < 2; ++it) {
        int i4 = tid + it * 256;
        int idx = i4 * 4;
        int c = idx >> 6, o = idx & 63;
        float4 w4 = *(const float4*)&wp[idx];
        short4v pk = { (short)f2bf(w4.x), (short)f2bf(w4.y),
                       (short)f2bf(w4.z), (short)f2bf(w4.w) };
        *(short4v*)&WpB[c * 72 + o] = pk;
    }

    const int w = tid >> 6;
    const int ln = tid & 63;
    const int sn = ln & 15;
    const int quad = ln >> 4;

    const float bcv = bc[w * 16 + sn];
    const float bp0 = bp[sn], bp1 = bp[16 + sn];

    __syncthreads();

    short8 b0 = *(const short8*)&WbT[(w * 16 + sn) * 96 + 0  + quad * 8];
    short8 b1 = *(const short8*)&WbT[(w * 16 + sn) * 96 + 32 + quad * 8];
    short8 b2 = *(const short8*)&WbT[(w * 16 + sn) * 96 + 64 + quad * 8];
    float4v zero = { 0.f, 0.f, 0.f, 0.f };
    float4v acc[4] = { zero, zero, zero, zero };
#pragma unroll
    for (int tm = 0; tm < 4; ++tm) {
        const unsigned short* ar = &Abuf[(tm * 16 + sn) * 96 + quad * 8];
        short8 a0 = *(const short8*)(ar + 0);
        short8 a1 = *(const short8*)(ar + 32);
        short8 a2 = *(const short8*)(ar + 64);
        acc[tm] = __builtin_amdgcn_mfma_f32_16x16x32_bf16(a0, b0, acc[tm], 0, 0, 0);
        acc[tm] = __builtin_amdgcn_mfma_f32_16x16x32_bf16(a1, b1, acc[tm], 0, 0, 0);
        acc[tm] = __builtin_amdgcn_mfma_f32_16x16x32_bf16(a2, b2, acc[tm], 0, 0, 0);
    }
#pragma unroll
    for (int tm = 0; tm < 4; ++tm) {
        float ge[4];
        ge[0] = gelu_exact(acc[tm].x + bcv);
        ge[1] = gelu_exact(acc[tm].y + bcv);
        ge[2] = gelu_exact(acc[tm].z + bcv);
        ge[3] = gelu_exact(acc[tm].w + bcv);
#pragma unroll
        for (int i = 0; i < 4; ++i)
            Hb[(tm * 16 + quad * 4 + i) * 72 + w * 16 + sn] = f2bf(ge[i]);
    }

    __syncthreads();

    const unsigned short* hr = &Hb[(w * 16 + sn) * 72 + quad * 8];
    short8 pa0 = *(const short8*)(hr + 0);
    short8 pa1 = *(const short8*)(hr + 32);
    short8 pb00 = *(const short8*)&WpB[sn * 72 + quad * 8];
    short8 pb01 = *(const short8*)&WpB[sn * 72 + 32 + quad * 8];
    short8 pb10 = *(const short8*)&WpB[(16 + sn) * 72 + quad * 8];
    short8 pb11 = *(const short8*)&WpB[(16 + sn) * 72 + 32 + quad * 8];
    float4v acc0 = zero, acc1 = zero;
    acc0 = __builtin_amdgcn_mfma_f32_16x16x32_bf16(pa0, pb00, acc0, 0, 0, 0);
    acc0 = __builtin_amdgcn_mfma_f32_16x16x32_bf16(pa1, pb01, acc0, 0, 0, 0);
    acc1 = __builtin_amdgcn_mfma_f32_16x16x32_bf16(pa0, pb10, acc1, 0, 0, 0);
    acc1 = __builtin_amdgcn_mfma_f32_16x16x32_bf16(pa1, pb11, acc1, 0, 0, 0);

    float v0[4] = { acc0.x + bp0, acc0.y + bp0, acc0.z + bp0, acc0.w + bp0 };
    float v1[4] = { acc1.x + bp1, acc1.y + bp1, acc1.z + bp1, acc1.w + bp1 };
#pragma unroll
    for (int i = 0; i < 4; ++i) {
        int t = w * 16 + quad * 4 + i;
        if (mode == 0) {
            size_t rowb = ((size_t)n * T_LEN + t0 + t) * 32;
            outb[rowb + sn]      = f2bf(v0[i]);
            outb[rowb + 16 + sn] = f2bf(v1[i]);
        } else {
            outb[((size_t)(n * 2 + 0) * 16 + sn) * T_LEN + t0 + t] = f2bf(v0[i]);
            outb[((size_t)(n * 2 + 1) * 16 + sn) * T_LEN + t0 + t] = f2bf(v1[i]);
        }
    }
}

// ---------------------------------------------------------------------------
// MFMA attention, split-S for occupancy: 2048 blocks (8/CU, 32 waves/CU).
// g = (bfh<<5) | (tt<<1) | half; wave = 16 q-rows x 512 s.
// Emits UNNORMALIZED partials: ynws[half] (y_num, C-layout) + lws[half]
// (row sums). Epilogue merges (yn0+yn1)/(l0+l1) during its staging loop.
// ---------------------------------------------------------------------------
__global__ __launch_bounds__(256) void attn_kernel(
    const unsigned short* __restrict__ qbf,   // [32][1024][32] bf16
    const unsigned short* __restrict__ kbf,   // [8][1024][32] bf16
    const unsigned short* __restrict__ vtbf,  // [8*2*16][1024] bf16 (V^T per head)
    float* __restrict__ ynws,                 // [2][32][1024][32] f32 partial y_num
    float* __restrict__ lws)                  // [2][32][2][1024] f32 partial l
{
    __shared__ unsigned short plds[4 * 16 * 36];

    const int tid = threadIdx.x;
    const int w = tid >> 6;
    const int ln = tid & 63;
    const int sn = ln & 15;
    const int quad = ln >> 4;
    const int g = blockIdx.x;
    const int half = g & 1;
    const int tt = (g >> 1) & 15;
    const int bfh = g >> 5;
    const int h = bfh & 1;
    const int bf = bfh >> 1;
    const int b = bf >> 2;
    const int trow = tt * 64 + w * 16 + sn;

    short8 aq = {0, 0, 0, 0, 0, 0, 0, 0};
    if (quad < 2)
        aq = *(const short8*)(qbf + ((size_t)bf * T_LEN + trow) * 32 + h * 16 + quad * 8);

    const unsigned short* kb = kbf + (size_t)b * T_LEN * 32 + h * 16 + quad * 8;
    const unsigned short* vb = vtbf + ((size_t)(b * 2 + h) * 16 + sn) * T_LEN + quad * 8;
    unsigned short* pw = plds + w * 576;

    float4v yacc = {0.f, 0.f, 0.f, 0.f};
    float l0 = 0.f, l1 = 0.f, l2 = 0.f, l3 = 0.f;
    const float SC = 0.36067376022224085f;    // 0.25 * log2(e)
    const int sbeg = half * 512;

#pragma unroll 1
    for (int s0 = sbeg; s0 < sbeg + 512; s0 += 32) {
        short8 bk0 = {0, 0, 0, 0, 0, 0, 0, 0};
        short8 bk1 = {0, 0, 0, 0, 0, 0, 0, 0};
        if (quad < 2) {
            bk0 = *(const short8*)(kb + (size_t)(s0 + sn) * 32);
            bk1 = *(const short8*)(kb + (size_t)(s0 + 16 + sn) * 32);
        }
        float4v z = {0.f, 0.f, 0.f, 0.f};
        float4v c0 = __builtin_amdgcn_mfma_f32_16x16x32_bf16(aq, bk0, z, 0, 0, 0);
        float4v c1 = __builtin_amdgcn_mfma_f32_16x16x32_bf16(aq, bk1, z, 0, 0, 0);

        float p00 = exp2f(c0.x * SC), p01 = exp2f(c0.y * SC);
        float p02 = exp2f(c0.z * SC), p03 = exp2f(c0.w * SC);
        float p10 = exp2f(c1.x * SC), p11 = exp2f(c1.y * SC);
        float p12 = exp2f(c1.z * SC), p13 = exp2f(c1.w * SC);
        l0 += p00 + p10; l1 += p01 + p11;
        l2 += p02 + p12; l3 += p03 + p13;

        const int tb = quad * 4;
        pw[(tb + 0) * 36 + sn]      = f2bf(p00);
        pw[(tb + 1) * 36 + sn]      = f2bf(p01);
        pw[(tb + 2) * 36 + sn]      = f2bf(p02);
        pw[(tb + 3) * 36 + sn]      = f2bf(p03);
        pw[(tb + 0) * 36 + 16 + sn] = f2bf(p10);
        pw[(tb + 1) * 36 + 16 + sn] = f2bf(p11);
        pw[(tb + 2) * 36 + 16 + sn] = f2bf(p12);
        pw[(tb + 3) * 36 + 16 + sn] = f2bf(p13);

        const unsigned short* pr = pw + sn * 36 + quad * 8;
        short4v plo = *(const short4v*)pr;
        short4v phi = *(const short4v*)(pr + 4);
        short8 ap = {plo.x, plo.y, plo.z, plo.w, phi.x, phi.y, phi.z, phi.w};

        short8 bv = *(const short8*)(vb + s0);
        yacc = __builtin_amdgcn_mfma_f32_16x16x32_bf16(ap, bv, yacc, 0, 0, 0);
    }

#pragma unroll
    for (int off = 1; off < 16; off <<= 1) {
        l0 += __shfl_xor(l0, off); l1 += __shfl_xor(l1, off);
        l2 += __shfl_xor(l2, off); l3 += __shfl_xor(l3, off);
    }

    float* yp = ynws + (((size_t)half * 32 + bf) * T_LEN + tt * 64 + w * 16 + quad * 4) * 32 + h * 16 + sn;
    yp[0 * 32] = yacc.x;
    yp[1 * 32] = yacc.y;
    yp[2 * 32] = yacc.z;
    yp[3 * 32] = yacc.w;
    if (sn == 0) {
        float* lp = lws + (((size_t)half * 32 + bf) * 2 + h) * T_LEN + tt * 64 + w * 16 + quad * 4;
        lp[0] = l0; lp[1] = l1; lp[2] = l2; lp[3] = l3;
    }
}

// ---------------------------------------------------------------------------
// Epilogue: merge attn partials, then out1 = cd + y@Wc^T; h = LN(out1)*ln_w;
// out = out1 + gelu(h@Wfc^T)@Wmp^T
// ---------------------------------------------------------------------------
__global__ __launch_bounds__(256) void epi_kernel(
    const float* __restrict__ cd, const float* __restrict__ ynws,
    const float* __restrict__ lws,
    const float* __restrict__ wcp, const float* __restrict__ lnw,
    const float* __restrict__ wfc, const float* __restrict__ wmp,
    float* __restrict__ out)
{
    __shared__ float sy[64][32];
    __shared__ float shn[8][36], sg[8][36];
    __shared__ float sln[32];

    const int tid = threadIdx.x;
    const int rl = tid >> 5, c = tid & 31;

    float wa[32], wb[32], wm[32];
#pragma unroll
    for (int j4 = 0; j4 < 8; ++j4) {
        float4 a = *(const float4*)(wcp + c * 32 + j4 * 4);
        wa[j4 * 4 + 0] = a.x; wa[j4 * 4 + 1] = a.y; wa[j4 * 4 + 2] = a.z; wa[j4 * 4 + 3] = a.w;
        float4 f = *(const float4*)(wfc + c * 32 + j4 * 4);
        wb[j4 * 4 + 0] = f.x; wb[j4 * 4 + 1] = f.y; wb[j4 * 4 + 2] = f.z; wb[j4 * 4 + 3] = f.w;
        float4 m = *(const float4*)(wmp + c * 32 + j4 * 4);
        wm[j4 * 4 + 0] = m.x; wm[j4 * 4 + 1] = m.y; wm[j4 * 4 + 2] = m.z; wm[j4 * 4 + 3] = m.w;
    }
    if (tid < 32) sln[tid] = lnw[tid];

    const int bf = blockIdx.x >> 4;
    const int t0 = (blockIdx.x & 15) * 64;
    const size_t base = (size_t)blockIdx.x * 64;
    {
        const float4* yn0 = (const float4*)ynws;
        const float4* yn1 = (const float4*)(ynws + (size_t)32 * T_LEN * 32);
        float4* ydst = (float4*)&sy[0][0];
        for (int i = tid; i < 512; i += 256) {
            int r = i >> 3, c4 = i & 7, hh = c4 >> 2;
            int t = t0 + r;
            float l = lws[((size_t)bf * 2 + hh) * T_LEN + t] +
                      lws[(((size_t)32 + bf) * 2 + hh) * T_LEN + t];
            float inv = 1.0f / l;
            float4 a = yn0[base * 8 + i];
            float4 b = yn1[base * 8 + i];
            float4 v;
            v.x = (a.x + b.x) * inv; v.y = (a.y + b.y) * inv;
            v.z = (a.z + b.z) * inv; v.w = (a.w + b.w) * inv;
            ydst[i] = v;
        }
    }
    __syncthreads();
    const float lnwc = sln[c];

#pragma unroll 1
    for (int p = 0; p < 8; ++p) {
        int r = p * 8 + rl;
        size_t row = base + r;
        float x1 = cd[row * 32 + c];
#pragma unroll
        for (int j4 = 0; j4 < 8; ++j4) {
            float4 yv = *(const float4*)&sy[r][j4 * 4];
            x1 += wa[j4 * 4 + 0] * yv.x + wa[j4 * 4 + 1] * yv.y +
                  wa[j4 * 4 + 2] * yv.z + wa[j4 * 4 + 3] * yv.w;
        }
        float s1 = x1, s2 = x1 * x1;
#pragma unroll
        for (int off = 16; off; off >>= 1) {
            s1 += __shfl_xor(s1, off);
            s2 += __shfl_xor(s2, off);
        }
        float mu = s1 * (1.0f / 32.0f);
        float var = s2 * (1.0f / 32.0f) - mu * mu;
        float hn = (x1 - mu) * rsqrtf(var + 1e-5f) * lnwc;
        shn[rl][c] = hn;
        float ga = 0.f;
#pragma unroll
        for (int j4 = 0; j4 < 8; ++j4) {
            float4 hv = *(const float4*)&shn[rl][j4 * 4];
            ga += wb[j4 * 4 + 0] * hv.x + wb[j4 * 4 + 1] * hv.y +
                  wb[j4 * 4 + 2] * hv.z + wb[j4 * 4 + 3] * hv.w;
        }
        float gv = gelu_exact(ga);
        sg[rl][c] = gv;
        float oa = x1;
#pragma unroll
        for (int j4 = 0; j4 < 8; ++j4) {
            float4 gvv = *(const float4*)&sg[rl][j4 * 4];
            oa += wm[j4 * 4 + 0] * gvv.x + wm[j4 * 4 + 1] * gvv.y +
                  wm[j4 * 4 + 2] * gvv.z + wm[j4 * 4 + 3] * gvv.w;
        }
        out[row * 32 + c] = oa;
    }
}

// ---------------------------------------------------------------------------
extern "C" void kernel_launch(void* const* d_in, const int* in_sizes, int n_in,
                              void* d_out, int out_size, void* d_ws, size_t ws_size,
                              hipStream_t stream) {
    const float* cd  = (const float*)d_in[0];
    const float* pkv = (const float*)d_in[1];
    const float* wqc = (const float*)d_in[2];
    const float* bqc = (const float*)d_in[3];
    const float* wqp = (const float*)d_in[4];
    const float* bqp = (const float*)d_in[5];
    const float* wkc = (const float*)d_in[6];
    const float* bkc = (const float*)d_in[7];
    const float* wkp = (const float*)d_in[8];
    const float* bkp = (const float*)d_in[9];
    const float* wvc = (const float*)d_in[10];
    const float* bvc = (const float*)d_in[11];
    const float* wvp = (const float*)d_in[12];
    const float* bvp = (const float*)d_in[13];
    const float* wcp = (const float*)d_in[14];
    const float* lnw = (const float*)d_in[15];
    const float* wfc = (const float*)d_in[16];
    const float* wmp = (const float*)d_in[17];

    // ws: qbf 2MB | kbf 0.5MB | vtbf 0.5MB | ynws 8MB | lws 0.5MB
    unsigned short* qbf  = (unsigned short*)d_ws;
    unsigned short* kbf  = qbf + (size_t)32 * 1024 * 32;
    unsigned short* vtbf = kbf + (size_t)8 * 1024 * 32;
    float* ynws = (float*)(vtbf + (size_t)8 * 1024 * 32);
    float* lws  = ynws + (size_t)2 * 32 * 1024 * 32;

    tcl_mfma<<<768, 256, 0, stream>>>(cd, pkv,
                                      wqc, bqc, wqp, bqp,
                                      wkc, bkc, wkp, bkp,
                                      wvc, bvc, wvp, bvp,
                                      qbf, kbf, vtbf);
    attn_kernel<<<2048, 256, 0, stream>>>(qbf, kbf, vtbf, ynws, lws);
    epi_kernel<<<512, 256, 0, stream>>>(cd, ynws, lws, wcp, lnw, wfc, wmp,
                                        (float*)d_out);
}

// Round 10
// 143.858 us; speedup vs baseline: 1.0208x; 1.0208x over previous
//
#include <hip/hip_runtime.h>

// B=8, F=4, T=S=1024, C=32, C2=64, NH=2, HD=16
// Inputs fp32, output fp32. q/k/v staged as bf16 for MFMA attention.
#define T_LEN 1024

typedef __attribute__((ext_vector_type(8))) short short8;   // 8 bf16 = 4 VGPR (MFMA A/B frag)
typedef __attribute__((ext_vector_type(4))) short short4v;
typedef __attribute__((ext_vector_type(4))) float float4v;  // MFMA C/D frag

__device__ __forceinline__ float gelu_exact(float x) {
    return 0.5f * x * (1.0f + erff(x * 0.70710678118654752440f));
}
__device__ __forceinline__ unsigned short f2bf(float f) {   // round-to-nearest-even
    unsigned u = __float_as_uint(f);
    u += 0x7fffu + ((u >> 16) & 1u);
    return (unsigned short)(u >> 16);
}

// ---------------------------------------------------------------------------
// MFMA TCL, 32 t-rows/block (halved serial depth vs R8), 1536 blocks:
//   [0,1024)    q from cd  -> qbf  [32][1024][32]
//   [1024,1280) k from pkv -> kbf  [8][1024][32]
//   [1280,1536) v from pkv -> vtbf [8][2][16][1024] (V^T)
// conv im2col GEMM: C[32x64] = A[32x96]*Wb -> 6 MFMAs/wave;
// proj [32x64]*[64x32] -> 2 MFMAs/wave. LDS ~28 KB -> ~5 blocks/CU.
// ---------------------------------------------------------------------------
__global__ __launch_bounds__(256) void tcl_mfma(
    const float* __restrict__ cd, const float* __restrict__ pkv,
    const float* __restrict__ wqc, const float* __restrict__ bqc,
    const float* __restrict__ wqp, const float* __restrict__ bqp,
    const float* __restrict__ wkc, const float* __restrict__ bkc,
    const float* __restrict__ wkp, const float* __restrict__ bkp,
    const float* __restrict__ wvc, const float* __restrict__ bvc,
    const float* __restrict__ wvp, const float* __restrict__ bvp,
    unsigned short* __restrict__ qbf, unsigned short* __restrict__ kbf,
    unsigned short* __restrict__ vtbf)
{
    __shared__ __align__(16) unsigned short Abuf[32 * 96];
    __shared__ __align__(16) unsigned short WbT[64 * 96];
    __shared__ __align__(16) unsigned short Hb[32 * 72];
    __shared__ __align__(16) unsigned short WpB[32 * 72];

    const int tid = threadIdx.x;
    const int gb = blockIdx.x;

    const float *src, *wc, *bc, *wp, *bp;
    unsigned short* outb;
    int n, mode;
    if (gb < 1024)      { n = gb >> 5;           src = cd;  wc = wqc; bc = bqc; wp = wqp; bp = bqp; outb = qbf;  mode = 0; }
    else if (gb < 1280) { n = (gb - 1024) >> 5;  src = pkv; wc = wkc; bc = bkc; wp = wkp; bp = bkp; outb = kbf;  mode = 0; }
    else                { n = (gb - 1280) >> 5;  src = pkv; wc = wvc; bc = bvc; wp = wvp; bp = bvp; outb = vtbf; mode = 1; }
    const int t0 = (gb & 31) * 32;

    // stage A (im2col, tap-major): 96 slices (t,tap) x 32 ch, 8 thr/slice
#pragma unroll
    for (int it = 0; it < 3; ++it) {
        int s = (tid + it * 256) >> 3;        // 0..95
        int sub = tid & 7;
        int t = s / 3, tap = s - t * 3;
        int tau = t0 + t - 2 + tap;
        float4 xv = make_float4(0.f, 0.f, 0.f, 0.f);
        if (tau >= 0) xv = *(const float4*)&src[((size_t)n * T_LEN + tau) * 32 + sub * 4];
        short4v pk = { (short)f2bf(xv.x), (short)f2bf(xv.y),
                       (short)f2bf(xv.z), (short)f2bf(xv.w) };
        *(short4v*)&Abuf[t * 96 + tap * 32 + sub * 4] = pk;
    }
    // stage WbT[o][tap*32+c] = wc[o*96 + c*3 + tap]
#pragma unroll
    for (int it = 0; it < 6; ++it) {
        int i4 = tid + it * 256;
        int idx = i4 * 4;
        int o = idx / 96, r = idx - o * 96;
        float4 w4 = *(const float4*)&wc[idx];
        float we[4] = { w4.x, w4.y, w4.z, w4.w };
#pragma unroll
        for (int e = 0; e < 4; ++e) {
            int re = r + e, c = re / 3, tap = re - c * 3;
            WbT[o * 96 + tap * 32 + c] = f2bf(we[e]);
        }
    }
    // stage WpB[c][o]
#pragma unroll
    for (int it = 0; it < 2; ++it) {
        int i4 = tid + it * 256;
        int idx = i4 * 4;
        int c = idx >> 6, o = idx & 63;
        float4 w4 = *(const float4*)&wp[idx];
        short4v pk = { (short)f2bf(w4.x), (short)f2bf(w4.y),
                       (short)f2bf(w4.z), (short)f2bf(w4.w) };
        *(short4v*)&WpB[c * 72 + o] = pk;
    }

    const int w = tid >> 6;
    const int ln = tid & 63;
    const int sn = ln & 15;
    const int quad = ln >> 4;

    const float bcv = bc[w * 16 + sn];        // conv: wave w = o-tile w
    const int tmw = w & 1, cnw = w >> 1;      // proj: wave w = (m,n) tile
    const float bpv = bp[cnw * 16 + sn];

    __syncthreads();

    // conv GEMM: wave w covers o-tile w, both t-tiles
    short8 b0 = *(const short8*)&WbT[(w * 16 + sn) * 96 + 0  + quad * 8];
    short8 b1 = *(const short8*)&WbT[(w * 16 + sn) * 96 + 32 + quad * 8];
    short8 b2 = *(const short8*)&WbT[(w * 16 + sn) * 96 + 64 + quad * 8];
    float4v zero = { 0.f, 0.f, 0.f, 0.f };
    float4v acc[2] = { zero, zero };
#pragma unroll
    for (int tm = 0; tm < 2; ++tm) {
        const unsigned short* ar = &Abuf[(tm * 16 + sn) * 96 + quad * 8];
        short8 a0 = *(const short8*)(ar + 0);
        short8 a1 = *(const short8*)(ar + 32);
        short8 a2 = *(const short8*)(ar + 64);
        acc[tm] = __builtin_amdgcn_mfma_f32_16x16x32_bf16(a0, b0, acc[tm], 0, 0, 0);
        acc[tm] = __builtin_amdgcn_mfma_f32_16x16x32_bf16(a1, b1, acc[tm], 0, 0, 0);
        acc[tm] = __builtin_amdgcn_mfma_f32_16x16x32_bf16(a2, b2, acc[tm], 0, 0, 0);
    }
#pragma unroll
    for (int tm = 0; tm < 2; ++tm) {
        float ge[4];
        ge[0] = gelu_exact(acc[tm].x + bcv);
        ge[1] = gelu_exact(acc[tm].y + bcv);
        ge[2] = gelu_exact(acc[tm].z + bcv);
        ge[3] = gelu_exact(acc[tm].w + bcv);
#pragma unroll
        for (int i = 0; i < 4; ++i)
            Hb[(tm * 16 + quad * 4 + i) * 72 + w * 16 + sn] = f2bf(ge[i]);
    }

    __syncthreads();

    // proj GEMM: wave w -> (t-tile tmw, c-tile cnw)
    const unsigned short* hr = &Hb[(tmw * 16 + sn) * 72 + quad * 8];
    short8 pa0 = *(const short8*)(hr + 0);
    short8 pa1 = *(const short8*)(hr + 32);
    short8 pb0 = *(const short8*)&WpB[(cnw * 16 + sn) * 72 + quad * 8];
    short8 pb1 = *(const short8*)&WpB[(cnw * 16 + sn) * 72 + 32 + quad * 8];
    float4v pacc = zero;
    pacc = __builtin_amdgcn_mfma_f32_16x16x32_bf16(pa0, pb0, pacc, 0, 0, 0);
    pacc = __builtin_amdgcn_mfma_f32_16x16x32_bf16(pa1, pb1, pacc, 0, 0, 0);

    float v[4] = { pacc.x + bpv, pacc.y + bpv, pacc.z + bpv, pacc.w + bpv };
#pragma unroll
    for (int i = 0; i < 4; ++i) {
        int t = tmw * 16 + quad * 4 + i;
        int c = cnw * 16 + sn;
        if (mode == 0) {
            outb[((size_t)n * T_LEN + t0 + t) * 32 + c] = f2bf(v[i]);
        } else {
            outb[((size_t)(n * 2 + cnw) * 16 + sn) * T_LEN + t0 + t] = f2bf(v[i]);
        }
    }
}

// ---------------------------------------------------------------------------
// MFMA attention, dual-stream ILP: 1024 blocks, wave = 16 q-rows x 1024 s.
// Each iteration processes TWO independent 32-s chunks (A,B) with separate
// P LDS buffers -> chains interleave in-wave, halving exposed latency.
// Layouts (m89-verified): A[m=ln&15][k=quad*8+j], B[k=quad*8+j][n=ln&15],
// C[row=quad*4+i][col=ln&15].
// ---------------------------------------------------------------------------
__global__ __launch_bounds__(256) void attn_kernel(
    const unsigned short* __restrict__ qbf,   // [32][1024][32] bf16
    const unsigned short* __restrict__ kbf,   // [8][1024][32] bf16
    const unsigned short* __restrict__ vtbf,  // [8*2*16][1024] bf16 (V^T per head)
    float* __restrict__ yws)                  // [32][1024][32] f32
{
    __shared__ unsigned short plds[4 * 2 * 16 * 36];   // per-wave dual P tiles

    const int tid = threadIdx.x;
    const int w = tid >> 6;
    const int ln = tid & 63;
    const int sn = ln & 15;
    const int quad = ln >> 4;
    const int g = blockIdx.x;
    const int tt = g & 15;
    const int bfh = g >> 4;
    const int h = bfh & 1;
    const int bf = bfh >> 1;
    const int b = bf >> 2;
    const int trow = tt * 64 + w * 16 + sn;

    short8 aq = {0, 0, 0, 0, 0, 0, 0, 0};
    if (quad < 2)
        aq = *(const short8*)(qbf + ((size_t)bf * T_LEN + trow) * 32 + h * 16 + quad * 8);

    const unsigned short* kb = kbf + (size_t)b * T_LEN * 32 + h * 16 + quad * 8;
    const unsigned short* vb = vtbf + ((size_t)(b * 2 + h) * 16 + sn) * T_LEN + quad * 8;
    unsigned short* pwA = plds + w * 1152;
    unsigned short* pwB = pwA + 576;

    float4v yacc = {0.f, 0.f, 0.f, 0.f};
    float l0 = 0.f, l1 = 0.f, l2 = 0.f, l3 = 0.f;
    const float SC = 0.36067376022224085f;    // 0.25 * log2(e)

#pragma unroll 1
    for (int s0 = 0; s0 < 1024; s0 += 64) {
        // --- loads for both streams up front
        short8 ka0 = {0,0,0,0,0,0,0,0}, ka1 = ka0, kb0 = ka0, kb1 = ka0;
        if (quad < 2) {
            ka0 = *(const short8*)(kb + (size_t)(s0 + sn) * 32);
            ka1 = *(const short8*)(kb + (size_t)(s0 + 16 + sn) * 32);
            kb0 = *(const short8*)(kb + (size_t)(s0 + 32 + sn) * 32);
            kb1 = *(const short8*)(kb + (size_t)(s0 + 48 + sn) * 32);
        }
        short8 bvA = *(const short8*)(vb + s0);
        short8 bvB = *(const short8*)(vb + s0 + 32);

        float4v z = {0.f, 0.f, 0.f, 0.f};
        float4v cA0 = __builtin_amdgcn_mfma_f32_16x16x32_bf16(aq, ka0, z, 0, 0, 0);
        float4v cA1 = __builtin_amdgcn_mfma_f32_16x16x32_bf16(aq, ka1, z, 0, 0, 0);
        float4v cB0 = __builtin_amdgcn_mfma_f32_16x16x32_bf16(aq, kb0, z, 0, 0, 0);
        float4v cB1 = __builtin_amdgcn_mfma_f32_16x16x32_bf16(aq, kb1, z, 0, 0, 0);

        float pA00 = exp2f(cA0.x * SC), pA01 = exp2f(cA0.y * SC);
        float pA02 = exp2f(cA0.z * SC), pA03 = exp2f(cA0.w * SC);
        float pA10 = exp2f(cA1.x * SC), pA11 = exp2f(cA1.y * SC);
        float pA12 = exp2f(cA1.z * SC), pA13 = exp2f(cA1.w * SC);
        float pB00 = exp2f(cB0.x * SC), pB01 = exp2f(cB0.y * SC);
        float pB02 = exp2f(cB0.z * SC), pB03 = exp2f(cB0.w * SC);
        float pB10 = exp2f(cB1.x * SC), pB11 = exp2f(cB1.y * SC);
        float pB12 = exp2f(cB1.z * SC), pB13 = exp2f(cB1.w * SC);

        l0 += (pA00 + pA10) + (pB00 + pB10);
        l1 += (pA01 + pA11) + (pB01 + pB11);
        l2 += (pA02 + pA12) + (pB02 + pB12);
        l3 += (pA03 + pA13) + (pB03 + pB13);

        const int tb = quad * 4;
        pwA[(tb + 0) * 36 + sn]      = f2bf(pA00);
        pwA[(tb + 1) * 36 + sn]      = f2bf(pA01);
        pwA[(tb + 2) * 36 + sn]      = f2bf(pA02);
        pwA[(tb + 3) * 36 + sn]      = f2bf(pA03);
        pwA[(tb + 0) * 36 + 16 + sn] = f2bf(pA10);
        pwA[(tb + 1) * 36 + 16 + sn] = f2bf(pA11);
        pwA[(tb + 2) * 36 + 16 + sn] = f2bf(pA12);
        pwA[(tb + 3) * 36 + 16 + sn] = f2bf(pA13);
        pwB[(tb + 0) * 36 + sn]      = f2bf(pB00);
        pwB[(tb + 1) * 36 + sn]      = f2bf(pB01);
        pwB[(tb + 2) * 36 + sn]      = f2bf(pB02);
        pwB[(tb + 3) * 36 + sn]      = f2bf(pB03);
        pwB[(tb + 0) * 36 + 16 + sn] = f2bf(pB10);
        pwB[(tb + 1) * 36 + 16 + sn] = f2bf(pB11);
        pwB[(tb + 2) * 36 + 16 + sn] = f2bf(pB12);
        pwB[(tb + 3) * 36 + 16 + sn] = f2bf(pB13);

        const unsigned short* prA = pwA + sn * 36 + quad * 8;
        const unsigned short* prB = pwB + sn * 36 + quad * 8;
        short4v aloA = *(const short4v*)prA;
        short4v ahiA = *(const short4v*)(prA + 4);
        short4v aloB = *(const short4v*)prB;
        short4v ahiB = *(const short4v*)(prB + 4);
        short8 apA = {aloA.x, aloA.y, aloA.z, aloA.w, ahiA.x, ahiA.y, ahiA.z, ahiA.w};
        short8 apB = {aloB.x, aloB.y, aloB.z, aloB.w, ahiB.x, ahiB.y, ahiB.z, ahiB.w};

        yacc = __builtin_amdgcn_mfma_f32_16x16x32_bf16(apA, bvA, yacc, 0, 0, 0);
        yacc = __builtin_amdgcn_mfma_f32_16x16x32_bf16(apB, bvB, yacc, 0, 0, 0);
    }

#pragma unroll
    for (int off = 1; off < 16; off <<= 1) {
        l0 += __shfl_xor(l0, off); l1 += __shfl_xor(l1, off);
        l2 += __shfl_xor(l2, off); l3 += __shfl_xor(l3, off);
    }
    const float i0 = 1.f / l0, i1 = 1.f / l1, i2 = 1.f / l2, i3 = 1.f / l3;

    float* yp = yws + ((size_t)bf * T_LEN + tt * 64 + w * 16 + quad * 4) * 32 + h * 16 + sn;
    yp[0 * 32] = yacc.x * i0;
    yp[1 * 32] = yacc.y * i1;
    yp[2 * 32] = yacc.z * i2;
    yp[3 * 32] = yacc.w * i3;
}

// ---------------------------------------------------------------------------
// Epilogue: out1 = cd + y@Wc^T; h = LN(out1)*ln_w; out = out1 + gelu(h@Wfc^T)@Wmp^T
// ---------------------------------------------------------------------------
__global__ __launch_bounds__(256) void epi_kernel(
    const float* __restrict__ cd, const float* __restrict__ yws,
    const float* __restrict__ wcp, const float* __restrict__ lnw,
    const float* __restrict__ wfc, const float* __restrict__ wmp,
    float* __restrict__ out)
{
    __shared__ float sy[64][32];
    __shared__ float shn[8][36], sg[8][36];
    __shared__ float sln[32];

    const int tid = threadIdx.x;
    const int rl = tid >> 5, c = tid & 31;

    float wa[32], wb[32], wm[32];
#pragma unroll
    for (int j4 = 0; j4 < 8; ++j4) {
        float4 a = *(const float4*)(wcp + c * 32 + j4 * 4);
        wa[j4 * 4 + 0] = a.x; wa[j4 * 4 + 1] = a.y; wa[j4 * 4 + 2] = a.z; wa[j4 * 4 + 3] = a.w;
        float4 f = *(const float4*)(wfc + c * 32 + j4 * 4);
        wb[j4 * 4 + 0] = f.x; wb[j4 * 4 + 1] = f.y; wb[j4 * 4 + 2] = f.z; wb[j4 * 4 + 3] = f.w;
        float4 m = *(const float4*)(wmp + c * 32 + j4 * 4);
        wm[j4 * 4 + 0] = m.x; wm[j4 * 4 + 1] = m.y; wm[j4 * 4 + 2] = m.z; wm[j4 * 4 + 3] = m.w;
    }
    if (tid < 32) sln[tid] = lnw[tid];

    const size_t base = (size_t)blockIdx.x * 64;
    {
        const float4* ysrc = (const float4*)(yws + base * 32);
        float4* ydst = (float4*)&sy[0][0];
        for (int i = tid; i < 512; i += 256) ydst[i] = ysrc[i];
    }
    __syncthreads();
    const float lnwc = sln[c];

#pragma unroll 1
    for (int p = 0; p < 8; ++p) {
        int r = p * 8 + rl;
        size_t row = base + r;
        float x1 = cd[row * 32 + c];
#pragma unroll
        for (int j4 = 0; j4 < 8; ++j4) {
            float4 yv = *(const float4*)&sy[r][j4 * 4];
            x1 += wa[j4 * 4 + 0] * yv.x + wa[j4 * 4 + 1] * yv.y +
                  wa[j4 * 4 + 2] * yv.z + wa[j4 * 4 + 3] * yv.w;
        }
        float s1 = x1, s2 = x1 * x1;
#pragma unroll
        for (int off = 16; off; off >>= 1) {
            s1 += __shfl_xor(s1, off);
            s2 += __shfl_xor(s2, off);
        }
        float mu = s1 * (1.0f / 32.0f);
        float var = s2 * (1.0f / 32.0f) - mu * mu;
        float hn = (x1 - mu) * rsqrtf(var + 1e-5f) * lnwc;
        shn[rl][c] = hn;
        float ga = 0.f;
#pragma unroll
        for (int j4 = 0; j4 < 8; ++j4) {
            float4 hv = *(const float4*)&shn[rl][j4 * 4];
            ga += wb[j4 * 4 + 0] * hv.x + wb[j4 * 4 + 1] * hv.y +
                  wb[j4 * 4 + 2] * hv.z + wb[j4 * 4 + 3] * hv.w;
        }
        float gv = gelu_exact(ga);
        sg[rl][c] = gv;
        float oa = x1;
#pragma unroll
        for (int j4 = 0; j4 < 8; ++j4) {
            float4 gvv = *(const float4*)&sg[rl][j4 * 4];
            oa += wm[j4 * 4 + 0] * gvv.x + wm[j4 * 4 + 1] * gvv.y +
                  wm[j4 * 4 + 2] * gvv.z + wm[j4 * 4 + 3] * gvv.w;
        }
        out[row * 32 + c] = oa;
    }
}

// ---------------------------------------------------------------------------
extern "C" void kernel_launch(void* const* d_in, const int* in_sizes, int n_in,
                              void* d_out, int out_size, void* d_ws, size_t ws_size,
                              hipStream_t stream) {
    const float* cd  = (const float*)d_in[0];
    const float* pkv = (const float*)d_in[1];
    const float* wqc = (const float*)d_in[2];
    const float* bqc = (const float*)d_in[3];
    const float* wqp = (const float*)d_in[4];
    const float* bqp = (const float*)d_in[5];
    const float* wkc = (const float*)d_in[6];
    const float* bkc = (const float*)d_in[7];
    const float* wkp = (const float*)d_in[8];
    const float* bkp = (const float*)d_in[9];
    const float* wvc = (const float*)d_in[10];
    const float* bvc = (const float*)d_in[11];
    const float* wvp = (const float*)d_in[12];
    const float* bvp = (const float*)d_in[13];
    const float* wcp = (const float*)d_in[14];
    const float* lnw = (const float*)d_in[15];
    const float* wfc = (const float*)d_in[16];
    const float* wmp = (const float*)d_in[17];

    // ws: qbf 2MB | kbf 0.5MB | vtbf 0.5MB | yws 4MB
    unsigned short* qbf  = (unsigned short*)d_ws;
    unsigned short* kbf  = qbf + (size_t)32 * 1024 * 32;
    unsigned short* vtbf = kbf + (size_t)8 * 1024 * 32;
    float* yws = (float*)(vtbf + (size_t)8 * 1024 * 32);

    tcl_mfma<<<1536, 256, 0, stream>>>(cd, pkv,
                                       wqc, bqc, wqp, bqp,
                                       wkc, bkc, wkp, bkp,
                                       wvc, bvc, wvp, bvp,
                                       qbf, kbf, vtbf);
    attn_kernel<<<1024, 256, 0, stream>>>(qbf, kbf, vtbf, yws);
    epi_kernel<<<512, 256, 0, stream>>>(cd, yws, wcp, lnw, wfc, wmp, (float*)d_out);
}

// Round 11
// 132.219 us; speedup vs baseline: 1.1106x; 1.0880x over previous
//
#include <hip/hip_runtime.h>

// B=8, F=4, T=S=1024, C=32, C2=64, NH=2, HD=16
// Inputs fp32, output fp32. k/v staged bf16 in ws; q stays in LDS (fused).
#define T_LEN 1024

typedef __attribute__((ext_vector_type(8))) short short8;   // 8 bf16 = 4 VGPR
typedef __attribute__((ext_vector_type(4))) short short4v;
typedef __attribute__((ext_vector_type(4))) float float4v;

__device__ __forceinline__ float gelu_exact(float x) {
    return 0.5f * x * (1.0f + erff(x * 0.70710678118654752440f));
}
__device__ __forceinline__ unsigned short f2bf(float f) {   // RNE
    unsigned u = __float_as_uint(f);
    u += 0x7fffu + ((u >> 16) & 1u);
    return (unsigned short)(u >> 16);
}

// ---------------------------------------------------------------------------
// kv_tcl: k/v TCL only (R10-proven structure), 512 blocks x 256 thr,
// 32-row tiles. [0,256): k -> kbf [8][1024][32]; [256,512): v -> vtbf
// [8][2][16][1024] (V^T).
// ---------------------------------------------------------------------------
__global__ __launch_bounds__(256) void kv_tcl(
    const float* __restrict__ pkv,
    const float* __restrict__ wkc, const float* __restrict__ bkc,
    const float* __restrict__ wkp, const float* __restrict__ bkp,
    const float* __restrict__ wvc, const float* __restrict__ bvc,
    const float* __restrict__ wvp, const float* __restrict__ bvp,
    unsigned short* __restrict__ kbf, unsigned short* __restrict__ vtbf)
{
    __shared__ __align__(16) unsigned short Abuf[32 * 96];
    __shared__ __align__(16) unsigned short WbT[64 * 96];
    __shared__ __align__(16) unsigned short Hb[32 * 72];
    __shared__ __align__(16) unsigned short WpB[32 * 72];

    const int tid = threadIdx.x;
    const int gb = blockIdx.x;

    const float *wc, *bc, *wp, *bp;
    unsigned short* outb;
    int n, mode;
    if (gb < 256) { n = gb >> 5;         wc = wkc; bc = bkc; wp = wkp; bp = bkp; outb = kbf;  mode = 0; }
    else          { n = (gb - 256) >> 5; wc = wvc; bc = bvc; wp = wvp; bp = bvp; outb = vtbf; mode = 1; }
    const int t0 = (gb & 31) * 32;

#pragma unroll
    for (int it = 0; it < 3; ++it) {
        int s = (tid + it * 256) >> 3;        // 0..95
        int sub = tid & 7;
        int t = s / 3, tap = s - t * 3;
        int tau = t0 + t - 2 + tap;
        float4 xv = make_float4(0.f, 0.f, 0.f, 0.f);
        if (tau >= 0) xv = *(const float4*)&pkv[((size_t)n * T_LEN + tau) * 32 + sub * 4];
        short4v pk = { (short)f2bf(xv.x), (short)f2bf(xv.y),
                       (short)f2bf(xv.z), (short)f2bf(xv.w) };
        *(short4v*)&Abuf[t * 96 + tap * 32 + sub * 4] = pk;
    }
#pragma unroll
    for (int it = 0; it < 6; ++it) {
        int i4 = tid + it * 256;
        int idx = i4 * 4;
        int o = idx / 96, r = idx - o * 96;
        float4 w4 = *(const float4*)&wc[idx];
        float we[4] = { w4.x, w4.y, w4.z, w4.w };
#pragma unroll
        for (int e = 0; e < 4; ++e) {
            int re = r + e, c = re / 3, tap = re - c * 3;
            WbT[o * 96 + tap * 32 + c] = f2bf(we[e]);
        }
    }
#pragma unroll
    for (int it = 0; it < 2; ++it) {
        int i4 = tid + it * 256;
        int idx = i4 * 4;
        int c = idx >> 6, o = idx & 63;
        float4 w4 = *(const float4*)&wp[idx];
        short4v pk = { (short)f2bf(w4.x), (short)f2bf(w4.y),
                       (short)f2bf(w4.z), (short)f2bf(w4.w) };
        *(short4v*)&WpB[c * 72 + o] = pk;
    }

    const int w = tid >> 6;
    const int ln = tid & 63;
    const int sn = ln & 15;
    const int quad = ln >> 4;

    const float bcv = bc[w * 16 + sn];
    const int tmw = w & 1, cnw = w >> 1;
    const float bpv = bp[cnw * 16 + sn];

    __syncthreads();

    short8 b0 = *(const short8*)&WbT[(w * 16 + sn) * 96 + 0  + quad * 8];
    short8 b1 = *(const short8*)&WbT[(w * 16 + sn) * 96 + 32 + quad * 8];
    short8 b2 = *(const short8*)&WbT[(w * 16 + sn) * 96 + 64 + quad * 8];
    float4v zero = { 0.f, 0.f, 0.f, 0.f };
    float4v acc[2] = { zero, zero };
#pragma unroll
    for (int tm = 0; tm < 2; ++tm) {
        const unsigned short* ar = &Abuf[(tm * 16 + sn) * 96 + quad * 8];
        short8 a0 = *(const short8*)(ar + 0);
        short8 a1 = *(const short8*)(ar + 32);
        short8 a2 = *(const short8*)(ar + 64);
        acc[tm] = __builtin_amdgcn_mfma_f32_16x16x32_bf16(a0, b0, acc[tm], 0, 0, 0);
        acc[tm] = __builtin_amdgcn_mfma_f32_16x16x32_bf16(a1, b1, acc[tm], 0, 0, 0);
        acc[tm] = __builtin_amdgcn_mfma_f32_16x16x32_bf16(a2, b2, acc[tm], 0, 0, 0);
    }
#pragma unroll
    for (int tm = 0; tm < 2; ++tm) {
        float ge[4];
        ge[0] = gelu_exact(acc[tm].x + bcv);
        ge[1] = gelu_exact(acc[tm].y + bcv);
        ge[2] = gelu_exact(acc[tm].z + bcv);
        ge[3] = gelu_exact(acc[tm].w + bcv);
#pragma unroll
        for (int i = 0; i < 4; ++i)
            Hb[(tm * 16 + quad * 4 + i) * 72 + w * 16 + sn] = f2bf(ge[i]);
    }

    __syncthreads();

    const unsigned short* hr = &Hb[(tmw * 16 + sn) * 72 + quad * 8];
    short8 pa0 = *(const short8*)(hr + 0);
    short8 pa1 = *(const short8*)(hr + 32);
    short8 pb0 = *(const short8*)&WpB[(cnw * 16 + sn) * 72 + quad * 8];
    short8 pb1 = *(const short8*)&WpB[(cnw * 16 + sn) * 72 + 32 + quad * 8];
    float4v pacc = zero;
    pacc = __builtin_amdgcn_mfma_f32_16x16x32_bf16(pa0, pb0, pacc, 0, 0, 0);
    pacc = __builtin_amdgcn_mfma_f32_16x16x32_bf16(pa1, pb1, pacc, 0, 0, 0);

    float v[4] = { pacc.x + bpv, pacc.y + bpv, pacc.z + bpv, pacc.w + bpv };
#pragma unroll
    for (int i = 0; i < 4; ++i) {
        int t = tmw * 16 + quad * 4 + i;
        int c = cnw * 16 + sn;
        if (mode == 0) {
            outb[((size_t)n * T_LEN + t0 + t) * 32 + c] = f2bf(v[i]);
        } else {
            outb[((size_t)(n * 2 + cnw) * 16 + sn) * T_LEN + t0 + t] = f2bf(v[i]);
        }
    }
}

// ---------------------------------------------------------------------------
// fused_qae: per (bf, t-tile of 64 rows): q-TCL -> LDS, attention (8 waves =
// 4 row-tiles x 2 heads, dual-stream), epilogue. 512 blocks x 512 threads.
// LDS phase-overlaid via one static char region (61952 B):
//   phase A: Abuf[0,12288) WbT[12288,24576) Hb[24576,33792) WpB[33792,38400)
//   persistent: qs[38400,43520) (pitch 40 shorts, 16B rows)
//   phase B: plds[43520,61952) (8 waves x dual 576-short P tiles)
//   phase C overlay on dead A-region: sy[0,8192) swc[8192] swf[12800]
//   swm[17408] sln[22016] shn[22144] sg[24448] (pitch 36 floats, 16B rows)
// ---------------------------------------------------------------------------
__global__ __launch_bounds__(512) void fused_qae(
    const float* __restrict__ cd,
    const float* __restrict__ wqc, const float* __restrict__ bqc,
    const float* __restrict__ wqp, const float* __restrict__ bqp,
    const unsigned short* __restrict__ kbf,
    const unsigned short* __restrict__ vtbf,
    const float* __restrict__ wcp, const float* __restrict__ lnw,
    const float* __restrict__ wfc, const float* __restrict__ wmp,
    float* __restrict__ out)
{
    __shared__ __align__(16) char smem[61952];
    unsigned short* Abuf = (unsigned short*)(smem);
    unsigned short* WbT  = (unsigned short*)(smem + 12288);
    unsigned short* Hb   = (unsigned short*)(smem + 24576);
    unsigned short* WpB  = (unsigned short*)(smem + 33792);
    unsigned short* qs   = (unsigned short*)(smem + 38400);
    unsigned short* plds = (unsigned short*)(smem + 43520);

    const int tid = threadIdx.x;
    const int bf = blockIdx.x >> 4;
    const int tt = blockIdx.x & 15;
    const int t0 = tt * 64;
    const int b = bf >> 2;

    // ---- phase A staging (512 threads)
#pragma unroll
    for (int it = 0; it < 3; ++it) {
        int idx = tid + it * 512;             // 0..1535
        int s = idx >> 3;                     // 0..191
        int sub = idx & 7;
        int t = s / 3, tap = s - t * 3;
        int tau = t0 + t - 2 + tap;
        float4 xv = make_float4(0.f, 0.f, 0.f, 0.f);
        if (tau >= 0) xv = *(const float4*)&cd[((size_t)bf * T_LEN + tau) * 32 + sub * 4];
        short4v pk = { (short)f2bf(xv.x), (short)f2bf(xv.y),
                       (short)f2bf(xv.z), (short)f2bf(xv.w) };
        *(short4v*)&Abuf[t * 96 + tap * 32 + sub * 4] = pk;
    }
#pragma unroll
    for (int it = 0; it < 3; ++it) {
        int i4 = tid + it * 512;              // 0..1535
        int idx = i4 * 4;
        int o = idx / 96, r = idx - o * 96;
        float4 w4 = *(const float4*)&wqc[idx];
        float we[4] = { w4.x, w4.y, w4.z, w4.w };
#pragma unroll
        for (int e = 0; e < 4; ++e) {
            int re = r + e, c = re / 3, tap = re - c * 3;
            WbT[o * 96 + tap * 32 + c] = f2bf(we[e]);
        }
    }
    {
        int idx = tid * 4;                    // 512 float4s
        int c = idx >> 6, o = idx & 63;
        float4 w4 = *(const float4*)&wqp[idx];
        short4v pk = { (short)f2bf(w4.x), (short)f2bf(w4.y),
                       (short)f2bf(w4.z), (short)f2bf(w4.w) };
        *(short4v*)&WpB[c * 72 + o] = pk;
    }

    const int w = tid >> 6;       // wave 0..7
    const int ln = tid & 63;
    const int sn = ln & 15;
    const int quad = ln >> 4;
    const float4v zero = { 0.f, 0.f, 0.f, 0.f };

    __syncthreads();

    // ---- phase A conv GEMM: wave w -> t-tile w&3, o-tiles {w>>2, w>>2+2}
    {
        const int tm = w & 3;
        const int on0 = w >> 2, on1 = on0 + 2;
        const unsigned short* ar = &Abuf[(tm * 16 + sn) * 96 + quad * 8];
        short8 a0 = *(const short8*)(ar + 0);
        short8 a1 = *(const short8*)(ar + 32);
        short8 a2 = *(const short8*)(ar + 64);
        const unsigned short* br0 = &WbT[(on0 * 16 + sn) * 96 + quad * 8];
        const unsigned short* br1 = &WbT[(on1 * 16 + sn) * 96 + quad * 8];
        float4v c0 = zero, c1 = zero;
        c0 = __builtin_amdgcn_mfma_f32_16x16x32_bf16(a0, *(const short8*)(br0 + 0),  c0, 0, 0, 0);
        c0 = __builtin_amdgcn_mfma_f32_16x16x32_bf16(a1, *(const short8*)(br0 + 32), c0, 0, 0, 0);
        c0 = __builtin_amdgcn_mfma_f32_16x16x32_bf16(a2, *(const short8*)(br0 + 64), c0, 0, 0, 0);
        c1 = __builtin_amdgcn_mfma_f32_16x16x32_bf16(a0, *(const short8*)(br1 + 0),  c1, 0, 0, 0);
        c1 = __builtin_amdgcn_mfma_f32_16x16x32_bf16(a1, *(const short8*)(br1 + 32), c1, 0, 0, 0);
        c1 = __builtin_amdgcn_mfma_f32_16x16x32_bf16(a2, *(const short8*)(br1 + 64), c1, 0, 0, 0);
        const float bc0 = bqc[on0 * 16 + sn], bc1 = bqc[on1 * 16 + sn];
        float g0[4] = { gelu_exact(c0.x + bc0), gelu_exact(c0.y + bc0),
                        gelu_exact(c0.z + bc0), gelu_exact(c0.w + bc0) };
        float g1[4] = { gelu_exact(c1.x + bc1), gelu_exact(c1.y + bc1),
                        gelu_exact(c1.z + bc1), gelu_exact(c1.w + bc1) };
#pragma unroll
        for (int i = 0; i < 4; ++i) {
            Hb[(tm * 16 + quad * 4 + i) * 72 + on0 * 16 + sn] = f2bf(g0[i]);
            Hb[(tm * 16 + quad * 4 + i) * 72 + on1 * 16 + sn] = f2bf(g1[i]);
        }
    }
    __syncthreads();

    // ---- phase A proj GEMM: wave w -> t-tile w&3, c-tile w>>2; q -> qs LDS
    {
        const int tm = w & 3, cn = w >> 2;
        const unsigned short* hr = &Hb[(tm * 16 + sn) * 72 + quad * 8];
        short8 pa0 = *(const short8*)(hr + 0);
        short8 pa1 = *(const short8*)(hr + 32);
        const unsigned short* wr_ = &WpB[(cn * 16 + sn) * 72 + quad * 8];
        short8 pb0 = *(const short8*)(wr_ + 0);
        short8 pb1 = *(const short8*)(wr_ + 32);
        float4v pacc = zero;
        pacc = __builtin_amdgcn_mfma_f32_16x16x32_bf16(pa0, pb0, pacc, 0, 0, 0);
        pacc = __builtin_amdgcn_mfma_f32_16x16x32_bf16(pa1, pb1, pacc, 0, 0, 0);
        const float bpv = bqp[cn * 16 + sn];
        float v[4] = { pacc.x + bpv, pacc.y + bpv, pacc.z + bpv, pacc.w + bpv };
#pragma unroll
        for (int i = 0; i < 4; ++i)
            qs[(tm * 16 + quad * 4 + i) * 40 + cn * 16 + sn] = f2bf(v[i]);
    }
    __syncthreads();

    // ---- phase B attention: wave w -> head h = w&1, row-tile rt = w>>1
    const int h = w & 1, rt = w >> 1;
    short8 aq = {0, 0, 0, 0, 0, 0, 0, 0};
    if (quad < 2)
        aq = *(const short8*)&qs[(rt * 16 + sn) * 40 + h * 16 + quad * 8];

    const unsigned short* kb = kbf + (size_t)b * T_LEN * 32 + h * 16 + quad * 8;
    const unsigned short* vb = vtbf + ((size_t)(b * 2 + h) * 16 + sn) * T_LEN + quad * 8;
    unsigned short* pwA = plds + w * 1152;
    unsigned short* pwB = pwA + 576;

    float4v yacc = zero;
    float l0 = 0.f, l1 = 0.f, l2 = 0.f, l3 = 0.f;
    const float SC = 0.36067376022224085f;    // 0.25 * log2(e)

#pragma unroll 1
    for (int s0 = 0; s0 < 1024; s0 += 64) {
        short8 ka0 = {0,0,0,0,0,0,0,0}, ka1 = ka0, kb0 = ka0, kb1 = ka0;
        if (quad < 2) {
            ka0 = *(const short8*)(kb + (size_t)(s0 + sn) * 32);
            ka1 = *(const short8*)(kb + (size_t)(s0 + 16 + sn) * 32);
            kb0 = *(const short8*)(kb + (size_t)(s0 + 32 + sn) * 32);
            kb1 = *(const short8*)(kb + (size_t)(s0 + 48 + sn) * 32);
        }
        short8 bvA = *(const short8*)(vb + s0);
        short8 bvB = *(const short8*)(vb + s0 + 32);

        float4v cA0 = __builtin_amdgcn_mfma_f32_16x16x32_bf16(aq, ka0, zero, 0, 0, 0);
        float4v cA1 = __builtin_amdgcn_mfma_f32_16x16x32_bf16(aq, ka1, zero, 0, 0, 0);
        float4v cB0 = __builtin_amdgcn_mfma_f32_16x16x32_bf16(aq, kb0, zero, 0, 0, 0);
        float4v cB1 = __builtin_amdgcn_mfma_f32_16x16x32_bf16(aq, kb1, zero, 0, 0, 0);

        float pA00 = exp2f(cA0.x * SC), pA01 = exp2f(cA0.y * SC);
        float pA02 = exp2f(cA0.z * SC), pA03 = exp2f(cA0.w * SC);
        float pA10 = exp2f(cA1.x * SC), pA11 = exp2f(cA1.y * SC);
        float pA12 = exp2f(cA1.z * SC), pA13 = exp2f(cA1.w * SC);
        float pB00 = exp2f(cB0.x * SC), pB01 = exp2f(cB0.y * SC);
        float pB02 = exp2f(cB0.z * SC), pB03 = exp2f(cB0.w * SC);
        float pB10 = exp2f(cB1.x * SC), pB11 = exp2f(cB1.y * SC);
        float pB12 = exp2f(cB1.z * SC), pB13 = exp2f(cB1.w * SC);

        l0 += (pA00 + pA10) + (pB00 + pB10);
        l1 += (pA01 + pA11) + (pB01 + pB11);
        l2 += (pA02 + pA12) + (pB02 + pB12);
        l3 += (pA03 + pA13) + (pB03 + pB13);

        const int tb = quad * 4;
        pwA[(tb + 0) * 36 + sn]      = f2bf(pA00);
        pwA[(tb + 1) * 36 + sn]      = f2bf(pA01);
        pwA[(tb + 2) * 36 + sn]      = f2bf(pA02);
        pwA[(tb + 3) * 36 + sn]      = f2bf(pA03);
        pwA[(tb + 0) * 36 + 16 + sn] = f2bf(pA10);
        pwA[(tb + 1) * 36 + 16 + sn] = f2bf(pA11);
        pwA[(tb + 2) * 36 + 16 + sn] = f2bf(pA12);
        pwA[(tb + 3) * 36 + 16 + sn] = f2bf(pA13);
        pwB[(tb + 0) * 36 + sn]      = f2bf(pB00);
        pwB[(tb + 1) * 36 + sn]      = f2bf(pB01);
        pwB[(tb + 2) * 36 + sn]      = f2bf(pB02);
        pwB[(tb + 3) * 36 + sn]      = f2bf(pB03);
        pwB[(tb + 0) * 36 + 16 + sn] = f2bf(pB10);
        pwB[(tb + 1) * 36 + 16 + sn] = f2bf(pB11);
        pwB[(tb + 2) * 36 + 16 + sn] = f2bf(pB12);
        pwB[(tb + 3) * 36 + 16 + sn] = f2bf(pB13);

        const unsigned short* prA = pwA + sn * 36 + quad * 8;
        const unsigned short* prB = pwB + sn * 36 + quad * 8;
        short4v aloA = *(const short4v*)prA;
        short4v ahiA = *(const short4v*)(prA + 4);
        short4v aloB = *(const short4v*)prB;
        short4v ahiB = *(const short4v*)(prB + 4);
        short8 apA = {aloA.x, aloA.y, aloA.z, aloA.w, ahiA.x, ahiA.y, ahiA.z, ahiA.w};
        short8 apB = {aloB.x, aloB.y, aloB.z, aloB.w, ahiB.x, ahiB.y, ahiB.z, ahiB.w};

        yacc = __builtin_amdgcn_mfma_f32_16x16x32_bf16(apA, bvA, yacc, 0, 0, 0);
        yacc = __builtin_amdgcn_mfma_f32_16x16x32_bf16(apB, bvB, yacc, 0, 0, 0);
    }

#pragma unroll
    for (int off = 1; off < 16; off <<= 1) {
        l0 += __shfl_xor(l0, off); l1 += __shfl_xor(l1, off);
        l2 += __shfl_xor(l2, off); l3 += __shfl_xor(l3, off);
    }

    // normalized y -> sy (overlays dead phase-A region)
    float* sy = (float*)smem;                 // [64][32]
    {
        const float i0 = 1.f / l0, i1 = 1.f / l1, i2 = 1.f / l2, i3 = 1.f / l3;
        const int r0 = rt * 16 + quad * 4;
        sy[(r0 + 0) * 32 + h * 16 + sn] = yacc.x * i0;
        sy[(r0 + 1) * 32 + h * 16 + sn] = yacc.y * i1;
        sy[(r0 + 2) * 32 + h * 16 + sn] = yacc.z * i2;
        sy[(r0 + 3) * 32 + h * 16 + sn] = yacc.w * i3;
    }
    __syncthreads();

    // ---- phase C epilogue
    float* swc = (float*)(smem + 8192);       // [32][36]
    float* swf = (float*)(smem + 12800);
    float* swm = (float*)(smem + 17408);
    float* sln = (float*)(smem + 22016);
    float* shn = (float*)(smem + 22144);      // [16][36]
    float* sgv = (float*)(smem + 24448);
    for (int i = tid; i < 1024; i += 512) {
        int r = i >> 5, cc = i & 31;
        swc[r * 36 + cc] = wcp[i];
        swf[r * 36 + cc] = wfc[i];
        swm[r * 36 + cc] = wmp[i];
    }
    if (tid < 32) sln[tid] = lnw[tid];
    __syncthreads();

    const int rl = tid >> 5, c = tid & 31;
    const float lnwc = sln[c];
#pragma unroll 1
    for (int p = 0; p < 4; ++p) {
        int r = p * 16 + rl;
        size_t row = (size_t)bf * T_LEN + t0 + r;
        float x1 = cd[row * 32 + c];
#pragma unroll
        for (int j4 = 0; j4 < 8; ++j4) {
            float4 yv = *(const float4*)&sy[r * 32 + j4 * 4];
            const float* wv = &swc[c * 36 + j4 * 4];
            x1 += wv[0] * yv.x + wv[1] * yv.y + wv[2] * yv.z + wv[3] * yv.w;
        }
        float s1 = x1, s2 = x1 * x1;
#pragma unroll
        for (int off = 16; off; off >>= 1) {
            s1 += __shfl_xor(s1, off);
            s2 += __shfl_xor(s2, off);
        }
        float mu = s1 * (1.0f / 32.0f);
        float var = s2 * (1.0f / 32.0f) - mu * mu;
        float hn = (x1 - mu) * rsqrtf(var + 1e-5f) * lnwc;
        shn[rl * 36 + c] = hn;
        float ga = 0.f;
#pragma unroll
        for (int j4 = 0; j4 < 8; ++j4) {
            float4 hv = *(const float4*)&shn[rl * 36 + j4 * 4];
            const float* wv = &swf[c * 36 + j4 * 4];
            ga += wv[0] * hv.x + wv[1] * hv.y + wv[2] * hv.z + wv[3] * hv.w;
        }
        float gv = gelu_exact(ga);
        sgv[rl * 36 + c] = gv;
        float oa = x1;
#pragma unroll
        for (int j4 = 0; j4 < 8; ++j4) {
            float4 gvv = *(const float4*)&sgv[rl * 36 + j4 * 4];
            const float* wv = &swm[c * 36 + j4 * 4];
            oa += wv[0] * gvv.x + wv[1] * gvv.y + wv[2] * gvv.z + wv[3] * gvv.w;
        }
        out[row * 32 + c] = oa;
    }
}

// ---------------------------------------------------------------------------
extern "C" void kernel_launch(void* const* d_in, const int* in_sizes, int n_in,
                              void* d_out, int out_size, void* d_ws, size_t ws_size,
                              hipStream_t stream) {
    const float* cd  = (const float*)d_in[0];
    const float* pkv = (const float*)d_in[1];
    const float* wqc = (const float*)d_in[2];
    const float* bqc = (const float*)d_in[3];
    const float* wqp = (const float*)d_in[4];
    const float* bqp = (const float*)d_in[5];
    const float* wkc = (const float*)d_in[6];
    const float* bkc = (const float*)d_in[7];
    const float* wkp = (const float*)d_in[8];
    const float* bkp = (const float*)d_in[9];
    const float* wvc = (const float*)d_in[10];
    const float* bvc = (const float*)d_in[11];
    const float* wvp = (const float*)d_in[12];
    const float* bvp = (const float*)d_in[13];
    const float* wcp = (const float*)d_in[14];
    const float* lnw = (const float*)d_in[15];
    const float* wfc = (const float*)d_in[16];
    const float* wmp = (const float*)d_in[17];

    // ws: kbf 0.5MB | vtbf 0.5MB
    unsigned short* kbf  = (unsigned short*)d_ws;
    unsigned short* vtbf = kbf + (size_t)8 * 1024 * 32;

    kv_tcl<<<512, 256, 0, stream>>>(pkv, wkc, bkc, wkp, bkp,
                                    wvc, bvc, wvp, bvp, kbf, vtbf);
    fused_qae<<<512, 512, 0, stream>>>(cd, wqc, bqc, wqp, bqp, kbf, vtbf,
                                       wcp, lnw, wfc, wmp, (float*)d_out);
}

// Round 12
// 132.069 us; speedup vs baseline: 1.1119x; 1.0011x over previous
//
#include <hip/hip_runtime.h>
#include <hip/hip_bf16.h>

// B=8, F=4, T=S=1024, C=32, C2=64, NH=2, HD=16
// Inputs fp32, output fp32. k/v staged bf16 in ws; q stays in LDS (fused).
#define T_LEN 1024

typedef __attribute__((ext_vector_type(8))) short short8;   // 8 bf16 = 4 VGPR
typedef __attribute__((ext_vector_type(4))) short short4v;
typedef __attribute__((ext_vector_type(4))) float float4v;

__device__ __forceinline__ float gelu_exact(float x) {
    return 0.5f * x * (1.0f + erff(x * 0.70710678118654752440f));
}
__device__ __forceinline__ unsigned short f2bf(float f) {   // RNE
    unsigned u = __float_as_uint(f);
    u += 0x7fffu + ((u >> 16) & 1u);
    return (unsigned short)(u >> 16);
}
__device__ __forceinline__ unsigned pk2bf(float a, float b) {  // (lo=a, hi=b)
    __hip_bfloat162 h = __float22bfloat162_rn(make_float2(a, b));
    unsigned u;
    __builtin_memcpy(&u, &h, 4);
    return u;
}

// ---------------------------------------------------------------------------
// kv_tcl: k/v TCL (R10-proven), 512 blocks x 256 thr, 32-row tiles.
// [0,256): k -> kbf [8][1024][32]; [256,512): v -> vtbf [8][2][16][1024].
// ---------------------------------------------------------------------------
__global__ __launch_bounds__(256) void kv_tcl(
    const float* __restrict__ pkv,
    const float* __restrict__ wkc, const float* __restrict__ bkc,
    const float* __restrict__ wkp, const float* __restrict__ bkp,
    const float* __restrict__ wvc, const float* __restrict__ bvc,
    const float* __restrict__ wvp, const float* __restrict__ bvp,
    unsigned short* __restrict__ kbf, unsigned short* __restrict__ vtbf)
{
    __shared__ __align__(16) unsigned short Abuf[32 * 96];
    __shared__ __align__(16) unsigned short WbT[64 * 96];
    __shared__ __align__(16) unsigned short Hb[32 * 72];
    __shared__ __align__(16) unsigned short WpB[32 * 72];

    const int tid = threadIdx.x;
    const int gb = blockIdx.x;

    const float *wc, *bc, *wp, *bp;
    unsigned short* outb;
    int n, mode;
    if (gb < 256) { n = gb >> 5;         wc = wkc; bc = bkc; wp = wkp; bp = bkp; outb = kbf;  mode = 0; }
    else          { n = (gb - 256) >> 5; wc = wvc; bc = bvc; wp = wvp; bp = bvp; outb = vtbf; mode = 1; }
    const int t0 = (gb & 31) * 32;

#pragma unroll
    for (int it = 0; it < 3; ++it) {
        int s = (tid + it * 256) >> 3;
        int sub = tid & 7;
        int t = s / 3, tap = s - t * 3;
        int tau = t0 + t - 2 + tap;
        float4 xv = make_float4(0.f, 0.f, 0.f, 0.f);
        if (tau >= 0) xv = *(const float4*)&pkv[((size_t)n * T_LEN + tau) * 32 + sub * 4];
        short4v pk = { (short)f2bf(xv.x), (short)f2bf(xv.y),
                       (short)f2bf(xv.z), (short)f2bf(xv.w) };
        *(short4v*)&Abuf[t * 96 + tap * 32 + sub * 4] = pk;
    }
#pragma unroll
    for (int it = 0; it < 6; ++it) {
        int i4 = tid + it * 256;
        int idx = i4 * 4;
        int o = idx / 96, r = idx - o * 96;
        float4 w4 = *(const float4*)&wc[idx];
        float we[4] = { w4.x, w4.y, w4.z, w4.w };
#pragma unroll
        for (int e = 0; e < 4; ++e) {
            int re = r + e, c = re / 3, tap = re - c * 3;
            WbT[o * 96 + tap * 32 + c] = f2bf(we[e]);
        }
    }
#pragma unroll
    for (int it = 0; it < 2; ++it) {
        int i4 = tid + it * 256;
        int idx = i4 * 4;
        int c = idx >> 6, o = idx & 63;
        float4 w4 = *(const float4*)&wp[idx];
        short4v pk = { (short)f2bf(w4.x), (short)f2bf(w4.y),
                       (short)f2bf(w4.z), (short)f2bf(w4.w) };
        *(short4v*)&WpB[c * 72 + o] = pk;
    }

    const int w = tid >> 6;
    const int ln = tid & 63;
    const int sn = ln & 15;
    const int quad = ln >> 4;

    const float bcv = bc[w * 16 + sn];
    const int tmw = w & 1, cnw = w >> 1;
    const float bpv = bp[cnw * 16 + sn];

    __syncthreads();

    short8 b0 = *(const short8*)&WbT[(w * 16 + sn) * 96 + 0  + quad * 8];
    short8 b1 = *(const short8*)&WbT[(w * 16 + sn) * 96 + 32 + quad * 8];
    short8 b2 = *(const short8*)&WbT[(w * 16 + sn) * 96 + 64 + quad * 8];
    float4v zero = { 0.f, 0.f, 0.f, 0.f };
    float4v acc[2] = { zero, zero };
#pragma unroll
    for (int tm = 0; tm < 2; ++tm) {
        const unsigned short* ar = &Abuf[(tm * 16 + sn) * 96 + quad * 8];
        short8 a0 = *(const short8*)(ar + 0);
        short8 a1 = *(const short8*)(ar + 32);
        short8 a2 = *(const short8*)(ar + 64);
        acc[tm] = __builtin_amdgcn_mfma_f32_16x16x32_bf16(a0, b0, acc[tm], 0, 0, 0);
        acc[tm] = __builtin_amdgcn_mfma_f32_16x16x32_bf16(a1, b1, acc[tm], 0, 0, 0);
        acc[tm] = __builtin_amdgcn_mfma_f32_16x16x32_bf16(a2, b2, acc[tm], 0, 0, 0);
    }
#pragma unroll
    for (int tm = 0; tm < 2; ++tm) {
        float ge[4];
        ge[0] = gelu_exact(acc[tm].x + bcv);
        ge[1] = gelu_exact(acc[tm].y + bcv);
        ge[2] = gelu_exact(acc[tm].z + bcv);
        ge[3] = gelu_exact(acc[tm].w + bcv);
#pragma unroll
        for (int i = 0; i < 4; ++i)
            Hb[(tm * 16 + quad * 4 + i) * 72 + w * 16 + sn] = f2bf(ge[i]);
    }

    __syncthreads();

    const unsigned short* hr = &Hb[(tmw * 16 + sn) * 72 + quad * 8];
    short8 pa0 = *(const short8*)(hr + 0);
    short8 pa1 = *(const short8*)(hr + 32);
    short8 pb0 = *(const short8*)&WpB[(cnw * 16 + sn) * 72 + quad * 8];
    short8 pb1 = *(const short8*)&WpB[(cnw * 16 + sn) * 72 + 32 + quad * 8];
    float4v pacc = zero;
    pacc = __builtin_amdgcn_mfma_f32_16x16x32_bf16(pa0, pb0, pacc, 0, 0, 0);
    pacc = __builtin_amdgcn_mfma_f32_16x16x32_bf16(pa1, pb1, pacc, 0, 0, 0);

    float v[4] = { pacc.x + bpv, pacc.y + bpv, pacc.z + bpv, pacc.w + bpv };
#pragma unroll
    for (int i = 0; i < 4; ++i) {
        int t = tmw * 16 + quad * 4 + i;
        int c = cnw * 16 + sn;
        if (mode == 0) {
            outb[((size_t)n * T_LEN + t0 + t) * 32 + c] = f2bf(v[i]);
        } else {
            outb[((size_t)(n * 2 + cnw) * 16 + sn) * T_LEN + t0 + t] = f2bf(v[i]);
        }
    }
}

// ---------------------------------------------------------------------------
// fused_qae: per (bf, 64-row t-tile): q-TCL -> LDS, attention (8 waves =
// 4 row-tiles x 2 heads, dual-stream), epilogue. 512 blocks x 512 threads.
// LDS overlay (43520 B total -> 3 blocks/CU, was 62 KB / 2):
//   phase A: Abuf[0,12288) WbT[12288,24576) Hb[24576,33792) WpB[33792,38400)
//   persistent: qs[38400,43520) (pitch 40 shorts; holds SC-prescaled q)
//   phase B: plds[0,18432) overlays dead Abuf/WbT; sy[24576,32768) overlays
//            dead Hb/WpB (disjoint from plds -> no race w/ stragglers)
//   phase C (after barrier, plds dead): swc@0 swf@4608 swm@9216 sln@13824
//            shn@13952 sg@16256 (pitch 36 floats)
// Softmax scale folded into qs (q*0.25*log2e) -> exp2 directly on QK output.
// ---------------------------------------------------------------------------
__global__ __launch_bounds__(512) void fused_qae(
    const float* __restrict__ cd,
    const float* __restrict__ wqc, const float* __restrict__ bqc,
    const float* __restrict__ wqp, const float* __restrict__ bqp,
    const unsigned short* __restrict__ kbf,
    const unsigned short* __restrict__ vtbf,
    const float* __restrict__ wcp, const float* __restrict__ lnw,
    const float* __restrict__ wfc, const float* __restrict__ wmp,
    float* __restrict__ out)
{
    __shared__ __align__(16) char smem[43520];
    unsigned short* Abuf = (unsigned short*)(smem);
    unsigned short* WbT  = (unsigned short*)(smem + 12288);
    unsigned short* Hb   = (unsigned short*)(smem + 24576);
    unsigned short* WpB  = (unsigned short*)(smem + 33792);
    unsigned short* qs   = (unsigned short*)(smem + 38400);
    unsigned short* plds = (unsigned short*)(smem);          // phase B overlay

    const int tid = threadIdx.x;
    const int bf = blockIdx.x >> 4;
    const int tt = blockIdx.x & 15;
    const int t0 = tt * 64;
    const int b = bf >> 2;
    const float SC = 0.36067376022224085f;    // 0.25 * log2(e)

    // ---- phase A staging (512 threads)
#pragma unroll
    for (int it = 0; it < 3; ++it) {
        int idx = tid + it * 512;             // 0..1535
        int s = idx >> 3;                     // 0..191
        int sub = idx & 7;
        int t = s / 3, tap = s - t * 3;
        int tau = t0 + t - 2 + tap;
        float4 xv = make_float4(0.f, 0.f, 0.f, 0.f);
        if (tau >= 0) xv = *(const float4*)&cd[((size_t)bf * T_LEN + tau) * 32 + sub * 4];
        short4v pk = { (short)f2bf(xv.x), (short)f2bf(xv.y),
                       (short)f2bf(xv.z), (short)f2bf(xv.w) };
        *(short4v*)&Abuf[t * 96 + tap * 32 + sub * 4] = pk;
    }
#pragma unroll
    for (int it = 0; it < 3; ++it) {
        int i4 = tid + it * 512;              // 0..1535
        int idx = i4 * 4;
        int o = idx / 96, r = idx - o * 96;
        float4 w4 = *(const float4*)&wqc[idx];
        float we[4] = { w4.x, w4.y, w4.z, w4.w };
#pragma unroll
        for (int e = 0; e < 4; ++e) {
            int re = r + e, c = re / 3, tap = re - c * 3;
            WbT[o * 96 + tap * 32 + c] = f2bf(we[e]);
        }
    }
    {
        int idx = tid * 4;                    // 512 float4s
        int c = idx >> 6, o = idx & 63;
        float4 w4 = *(const float4*)&wqp[idx];
        short4v pk = { (short)f2bf(w4.x), (short)f2bf(w4.y),
                       (short)f2bf(w4.z), (short)f2bf(w4.w) };
        *(short4v*)&WpB[c * 72 + o] = pk;
    }

    const int w = tid >> 6;       // wave 0..7
    const int ln = tid & 63;
    const int sn = ln & 15;
    const int quad = ln >> 4;
    const float4v zero = { 0.f, 0.f, 0.f, 0.f };

    __syncthreads();

    // ---- phase A conv GEMM: wave w -> t-tile w&3, o-tiles {w>>2, w>>2+2}
    {
        const int tm = w & 3;
        const int on0 = w >> 2, on1 = on0 + 2;
        const unsigned short* ar = &Abuf[(tm * 16 + sn) * 96 + quad * 8];
        short8 a0 = *(const short8*)(ar + 0);
        short8 a1 = *(const short8*)(ar + 32);
        short8 a2 = *(const short8*)(ar + 64);
        const unsigned short* br0 = &WbT[(on0 * 16 + sn) * 96 + quad * 8];
        const unsigned short* br1 = &WbT[(on1 * 16 + sn) * 96 + quad * 8];
        float4v c0 = zero, c1 = zero;
        c0 = __builtin_amdgcn_mfma_f32_16x16x32_bf16(a0, *(const short8*)(br0 + 0),  c0, 0, 0, 0);
        c0 = __builtin_amdgcn_mfma_f32_16x16x32_bf16(a1, *(const short8*)(br0 + 32), c0, 0, 0, 0);
        c0 = __builtin_amdgcn_mfma_f32_16x16x32_bf16(a2, *(const short8*)(br0 + 64), c0, 0, 0, 0);
        c1 = __builtin_amdgcn_mfma_f32_16x16x32_bf16(a0, *(const short8*)(br1 + 0),  c1, 0, 0, 0);
        c1 = __builtin_amdgcn_mfma_f32_16x16x32_bf16(a1, *(const short8*)(br1 + 32), c1, 0, 0, 0);
        c1 = __builtin_amdgcn_mfma_f32_16x16x32_bf16(a2, *(const short8*)(br1 + 64), c1, 0, 0, 0);
        const float bc0 = bqc[on0 * 16 + sn], bc1 = bqc[on1 * 16 + sn];
        float g0[4] = { gelu_exact(c0.x + bc0), gelu_exact(c0.y + bc0),
                        gelu_exact(c0.z + bc0), gelu_exact(c0.w + bc0) };
        float g1[4] = { gelu_exact(c1.x + bc1), gelu_exact(c1.y + bc1),
                        gelu_exact(c1.z + bc1), gelu_exact(c1.w + bc1) };
#pragma unroll
        for (int i = 0; i < 4; ++i) {
            Hb[(tm * 16 + quad * 4 + i) * 72 + on0 * 16 + sn] = f2bf(g0[i]);
            Hb[(tm * 16 + quad * 4 + i) * 72 + on1 * 16 + sn] = f2bf(g1[i]);
        }
    }
    __syncthreads();

    // ---- phase A proj GEMM -> qs (pre-scaled by SC)
    {
        const int tm = w & 3, cn = w >> 2;
        const unsigned short* hr = &Hb[(tm * 16 + sn) * 72 + quad * 8];
        short8 pa0 = *(const short8*)(hr + 0);
        short8 pa1 = *(const short8*)(hr + 32);
        const unsigned short* wr_ = &WpB[(cn * 16 + sn) * 72 + quad * 8];
        short8 pb0 = *(const short8*)(wr_ + 0);
        short8 pb1 = *(const short8*)(wr_ + 32);
        float4v pacc = zero;
        pacc = __builtin_amdgcn_mfma_f32_16x16x32_bf16(pa0, pb0, pacc, 0, 0, 0);
        pacc = __builtin_amdgcn_mfma_f32_16x16x32_bf16(pa1, pb1, pacc, 0, 0, 0);
        const float bpv = bqp[cn * 16 + sn];
        float v[4] = { (pacc.x + bpv) * SC, (pacc.y + bpv) * SC,
                       (pacc.z + bpv) * SC, (pacc.w + bpv) * SC };
#pragma unroll
        for (int i = 0; i < 4; ++i)
            qs[(tm * 16 + quad * 4 + i) * 40 + cn * 16 + sn] = f2bf(v[i]);
    }
    __syncthreads();

    // ---- phase B attention: wave w -> head h = w&1, row-tile rt = w>>1
    const int h = w & 1, rt = w >> 1;
    short8 aq = {0, 0, 0, 0, 0, 0, 0, 0};
    if (quad < 2)
        aq = *(const short8*)&qs[(rt * 16 + sn) * 40 + h * 16 + quad * 8];

    const unsigned short* kb = kbf + (size_t)b * T_LEN * 32 + h * 16 + quad * 8;
    const unsigned short* vb = vtbf + ((size_t)(b * 2 + h) * 16 + sn) * T_LEN + quad * 8;
    unsigned short* pwA = plds + w * 1152;
    unsigned short* pwB = pwA + 576;

    float4v yacc = zero;
    float l0 = 0.f, l1 = 0.f, l2 = 0.f, l3 = 0.f;

#pragma unroll 1
    for (int s0 = 0; s0 < 1024; s0 += 64) {
        short8 ka0 = {0,0,0,0,0,0,0,0}, ka1 = ka0, kb0 = ka0, kb1 = ka0;
        if (quad < 2) {
            ka0 = *(const short8*)(kb + (size_t)(s0 + sn) * 32);
            ka1 = *(const short8*)(kb + (size_t)(s0 + 16 + sn) * 32);
            kb0 = *(const short8*)(kb + (size_t)(s0 + 32 + sn) * 32);
            kb1 = *(const short8*)(kb + (size_t)(s0 + 48 + sn) * 32);
        }
        short8 bvA = *(const short8*)(vb + s0);
        short8 bvB = *(const short8*)(vb + s0 + 32);

        float4v cA0 = __builtin_amdgcn_mfma_f32_16x16x32_bf16(aq, ka0, zero, 0, 0, 0);
        float4v cA1 = __builtin_amdgcn_mfma_f32_16x16x32_bf16(aq, ka1, zero, 0, 0, 0);
        float4v cB0 = __builtin_amdgcn_mfma_f32_16x16x32_bf16(aq, kb0, zero, 0, 0, 0);
        float4v cB1 = __builtin_amdgcn_mfma_f32_16x16x32_bf16(aq, kb1, zero, 0, 0, 0);

        // q pre-scaled -> exp2 directly on MFMA output
        float a0x = exp2f(cA0.x), a0y = exp2f(cA0.y), a0z = exp2f(cA0.z), a0w = exp2f(cA0.w);
        float a1x = exp2f(cA1.x), a1y = exp2f(cA1.y), a1z = exp2f(cA1.z), a1w = exp2f(cA1.w);
        float b0x = exp2f(cB0.x), b0y = exp2f(cB0.y), b0z = exp2f(cB0.z), b0w = exp2f(cB0.w);
        float b1x = exp2f(cB1.x), b1y = exp2f(cB1.y), b1z = exp2f(cB1.z), b1w = exp2f(cB1.w);

        l0 += (a0x + a1x) + (b0x + b1x);
        l1 += (a0y + a1y) + (b0y + b1y);
        l2 += (a0z + a1z) + (b0z + b1z);
        l3 += (a0w + a1w) + (b0w + b1w);

        const int tb = quad * 4;
        // packed bf16 conversion: (col sn, col 16+sn) per row
        unsigned uA0 = pk2bf(a0x, a1x), uA1 = pk2bf(a0y, a1y);
        unsigned uA2 = pk2bf(a0z, a1z), uA3 = pk2bf(a0w, a1w);
        unsigned uB0 = pk2bf(b0x, b1x), uB1 = pk2bf(b0y, b1y);
        unsigned uB2 = pk2bf(b0z, b1z), uB3 = pk2bf(b0w, b1w);
        pwA[(tb + 0) * 36 + sn]      = (unsigned short)uA0;
        pwA[(tb + 0) * 36 + 16 + sn] = (unsigned short)(uA0 >> 16);
        pwA[(tb + 1) * 36 + sn]      = (unsigned short)uA1;
        pwA[(tb + 1) * 36 + 16 + sn] = (unsigned short)(uA1 >> 16);
        pwA[(tb + 2) * 36 + sn]      = (unsigned short)uA2;
        pwA[(tb + 2) * 36 + 16 + sn] = (unsigned short)(uA2 >> 16);
        pwA[(tb + 3) * 36 + sn]      = (unsigned short)uA3;
        pwA[(tb + 3) * 36 + 16 + sn] = (unsigned short)(uA3 >> 16);
        pwB[(tb + 0) * 36 + sn]      = (unsigned short)uB0;
        pwB[(tb + 0) * 36 + 16 + sn] = (unsigned short)(uB0 >> 16);
        pwB[(tb + 1) * 36 + sn]      = (unsigned short)uB1;
        pwB[(tb + 1) * 36 + 16 + sn] = (unsigned short)(uB1 >> 16);
        pwB[(tb + 2) * 36 + sn]      = (unsigned short)uB2;
        pwB[(tb + 2) * 36 + 16 + sn] = (unsigned short)(uB2 >> 16);
        pwB[(tb + 3) * 36 + sn]      = (unsigned short)uB3;
        pwB[(tb + 3) * 36 + 16 + sn] = (unsigned short)(uB3 >> 16);

        const unsigned short* prA = pwA + sn * 36 + quad * 8;
        const unsigned short* prB = pwB + sn * 36 + quad * 8;
        short4v aloA = *(const short4v*)prA;
        short4v ahiA = *(const short4v*)(prA + 4);
        short4v aloB = *(const short4v*)prB;
        short4v ahiB = *(const short4v*)(prB + 4);
        short8 apA = {aloA.x, aloA.y, aloA.z, aloA.w, ahiA.x, ahiA.y, ahiA.z, ahiA.w};
        short8 apB = {aloB.x, aloB.y, aloB.z, aloB.w, ahiB.x, ahiB.y, ahiB.z, ahiB.w};

        yacc = __builtin_amdgcn_mfma_f32_16x16x32_bf16(apA, bvA, yacc, 0, 0, 0);
        yacc = __builtin_amdgcn_mfma_f32_16x16x32_bf16(apB, bvB, yacc, 0, 0, 0);
    }

#pragma unroll
    for (int off = 1; off < 16; off <<= 1) {
        l0 += __shfl_xor(l0, off); l1 += __shfl_xor(l1, off);
        l2 += __shfl_xor(l2, off); l3 += __shfl_xor(l3, off);
    }

    // normalized y -> sy (overlays dead Hb/WpB; disjoint from plds)
    float* sy = (float*)(smem + 24576);       // [64][32]
    {
        const float i0 = 1.f / l0, i1 = 1.f / l1, i2 = 1.f / l2, i3 = 1.f / l3;
        const int r0 = rt * 16 + quad * 4;
        sy[(r0 + 0) * 32 + h * 16 + sn] = yacc.x * i0;
        sy[(r0 + 1) * 32 + h * 16 + sn] = yacc.y * i1;
        sy[(r0 + 2) * 32 + h * 16 + sn] = yacc.z * i2;
        sy[(r0 + 3) * 32 + h * 16 + sn] = yacc.w * i3;
    }
    __syncthreads();   // all plds reads done before phase C overwrites [0,..)

    // ---- phase C epilogue (overlays dead plds region)
    float* swc = (float*)(smem + 0);          // [32][36]
    float* swf = (float*)(smem + 4608);
    float* swm = (float*)(smem + 9216);
    float* sln = (float*)(smem + 13824);
    float* shn = (float*)(smem + 13952);      // [16][36]
    float* sgv = (float*)(smem + 16256);
    for (int i = tid; i < 1024; i += 512) {
        int r = i >> 5, cc = i & 31;
        swc[r * 36 + cc] = wcp[i];
        swf[r * 36 + cc] = wfc[i];
        swm[r * 36 + cc] = wmp[i];
    }
    if (tid < 32) sln[tid] = lnw[tid];
    __syncthreads();

    const int rl = tid >> 5, c = tid & 31;
    const float lnwc = sln[c];
#pragma unroll 1
    for (int p = 0; p < 4; ++p) {
        int r = p * 16 + rl;
        size_t row = (size_t)bf * T_LEN + t0 + r;
        float x1 = cd[row * 32 + c];
#pragma unroll
        for (int j4 = 0; j4 < 8; ++j4) {
            float4 yv = *(const float4*)&sy[r * 32 + j4 * 4];
            const float* wv = &swc[c * 36 + j4 * 4];
            x1 += wv[0] * yv.x + wv[1] * yv.y + wv[2] * yv.z + wv[3] * yv.w;
        }
        float s1 = x1, s2 = x1 * x1;
#pragma unroll
        for (int off = 16; off; off >>= 1) {
            s1 += __shfl_xor(s1, off);
            s2 += __shfl_xor(s2, off);
        }
        float mu = s1 * (1.0f / 32.0f);
        float var = s2 * (1.0f / 32.0f) - mu * mu;
        float hn = (x1 - mu) * rsqrtf(var + 1e-5f) * lnwc;
        shn[rl * 36 + c] = hn;
        float ga = 0.f;
#pragma unroll
        for (int j4 = 0; j4 < 8; ++j4) {
            float4 hv = *(const float4*)&shn[rl * 36 + j4 * 4];
            const float* wv = &swf[c * 36 + j4 * 4];
            ga += wv[0] * hv.x + wv[1] * hv.y + wv[2] * hv.z + wv[3] * hv.w;
        }
        float gv = gelu_exact(ga);
        sgv[rl * 36 + c] = gv;
        float oa = x1;
#pragma unroll
        for (int j4 = 0; j4 < 8; ++j4) {
            float4 gvv = *(const float4*)&sgv[rl * 36 + j4 * 4];
            const float* wv = &swm[c * 36 + j4 * 4];
            oa += wv[0] * gvv.x + wv[1] * gvv.y + wv[2] * gvv.z + wv[3] * gvv.w;
        }
        out[row * 32 + c] = oa;
    }
}

// ---------------------------------------------------------------------------
extern "C" void kernel_launch(void* const* d_in, const int* in_sizes, int n_in,
                              void* d_out, int out_size, void* d_ws, size_t ws_size,
                              hipStream_t stream) {
    const float* cd  = (const float*)d_in[0];
    const float* pkv = (const float*)d_in[1];
    const float* wqc = (const float*)d_in[2];
    const float* bqc = (const float*)d_in[3];
    const float* wqp = (const float*)d_in[4];
    const float* bqp = (const float*)d_in[5];
    const float* wkc = (const float*)d_in[6];
    const float* bkc = (const float*)d_in[7];
    const float* wkp = (const float*)d_in[8];
    const float* bkp = (const float*)d_in[9];
    const float* wvc = (const float*)d_in[10];
    const float* bvc = (const float*)d_in[11];
    const float* wvp = (const float*)d_in[12];
    const float* bvp = (const float*)d_in[13];
    const float* wcp = (const float*)d_in[14];
    const float* lnw = (const float*)d_in[15];
    const float* wfc = (const float*)d_in[16];
    const float* wmp = (const float*)d_in[17];

    // ws: kbf 0.5MB | vtbf 0.5MB
    unsigned short* kbf  = (unsigned short*)d_ws;
    unsigned short* vtbf = kbf + (size_t)8 * 1024 * 32;

    kv_tcl<<<512, 256, 0, stream>>>(pkv, wkc, bkc, wkp, bkp,
                                    wvc, bvc, wvp, bvp, kbf, vtbf);
    fused_qae<<<512, 512, 0, stream>>>(cd, wqc, bqc, wqp, bqp, kbf, vtbf,
                                       wcp, lnw, wfc, wmp, (float*)d_out);
}